// Round 1
// baseline (159.995 us; speedup 1.0000x reference)
//
#include <hip/hip_runtime.h>

// Warp: trilinear grid_sample, padding_mode='zeros', align_corners=true.
// image: (B=2, C=1, H=128, W=128, D=128) fp32
// ddf:   (B=2, 3, H, W, D) fp32, voxel-unit displacements
// out:   (B, C, H, W, D) fp32

constexpr int H = 128, W = 128, D = 128;
constexpr int N = H * W * D;      // 2^21
constexpr int B = 2;

__global__ __launch_bounds__(256) void warp_kernel(
    const float* __restrict__ image,
    const float* __restrict__ ddf,
    float* __restrict__ out)
{
    int tid = blockIdx.x * blockDim.x + threadIdx.x;
    if (tid >= B * N) return;

    int b   = tid >> 21;          // N = 2^21
    int lin = tid & (N - 1);
    int h = lin >> 14;            // W*D = 2^14
    int w = (lin >> 7) & 127;
    int d = lin & 127;

    const float* ddfb = ddf + (size_t)b * 3 * N + lin;
    float x = (float)h + ddfb[0];
    float y = (float)w + ddfb[N];
    float z = (float)d + ddfb[2 * N];

    float xf = floorf(x), yf = floorf(y), zf = floorf(z);
    float fx = x - xf, fy = y - yf, fz = z - zf;
    int x0 = (int)xf, y0 = (int)yf, z0 = (int)zf;
    int x1 = x0 + 1, y1 = y0 + 1, z1 = z0 + 1;

    // Per-axis weights with zero-padding folded in (weight=0 if OOB).
    bool vx0 = (unsigned)x0 < (unsigned)H;
    bool vx1 = (unsigned)x1 < (unsigned)H;
    bool vy0 = (unsigned)y0 < (unsigned)W;
    bool vy1 = (unsigned)y1 < (unsigned)W;
    bool vz0 = (unsigned)z0 < (unsigned)D;
    bool vz1 = (unsigned)z1 < (unsigned)D;

    float ax0 = vx0 ? (1.0f - fx) : 0.0f;
    float ax1 = vx1 ? fx          : 0.0f;
    float ay0 = vy0 ? (1.0f - fy) : 0.0f;
    float ay1 = vy1 ? fy          : 0.0f;
    float az0 = vz0 ? (1.0f - fz) : 0.0f;
    float az1 = vz1 ? fz          : 0.0f;

    // Clamped indices so every fetch is in-bounds (weight already zeroed).
    int cx0 = vx0 ? x0 : 0;
    int cx1 = vx1 ? x1 : 0;
    int cy0 = vy0 ? y0 : 0;
    int cy1 = vy1 ? y1 : 0;
    int cz0 = vz0 ? z0 : 0;
    int cz1 = vz1 ? z1 : 0;

    const float* img = image + (size_t)b * N;
    int rx0 = cx0 << 14, rx1 = cx1 << 14;   // x * W*D
    int ry0 = cy0 << 7,  ry1 = cy1 << 7;    // y * D

    float v000 = img[rx0 + ry0 + cz0];
    float v001 = img[rx0 + ry0 + cz1];
    float v010 = img[rx0 + ry1 + cz0];
    float v011 = img[rx0 + ry1 + cz1];
    float v100 = img[rx1 + ry0 + cz0];
    float v101 = img[rx1 + ry0 + cz1];
    float v110 = img[rx1 + ry1 + cz0];
    float v111 = img[rx1 + ry1 + cz1];

    float acc =
        ax0 * (ay0 * (az0 * v000 + az1 * v001) +
               ay1 * (az0 * v010 + az1 * v011)) +
        ax1 * (ay0 * (az0 * v100 + az1 * v101) +
               ay1 * (az0 * v110 + az1 * v111));

    out[tid] = acc;
}

extern "C" void kernel_launch(void* const* d_in, const int* in_sizes, int n_in,
                              void* d_out, int out_size, void* d_ws, size_t ws_size,
                              hipStream_t stream) {
    const float* image = (const float*)d_in[0];
    const float* ddf   = (const float*)d_in[1];
    float* out = (float*)d_out;

    int total = B * N;                      // 4,194,304
    int block = 256;
    int grid = (total + block - 1) / block; // 16384
    warp_kernel<<<grid, block, 0, stream>>>(image, ddf, out);
}

// Round 2
// 148.223 us; speedup vs baseline: 1.0794x; 1.0794x over previous
//
#include <hip/hip_runtime.h>

// Warp: trilinear grid_sample, padding_mode='zeros', align_corners=true.
// image: (B=2, C=1, H=128, W=128, D=128) fp32
// ddf:   (B=2, 3, H, W, D) fp32, voxel-unit displacements
// out:   (B, C, H, W, D) fp32
//
// Bottleneck (R1 rocprof): VMEM request rate on scattered gathers, not HBM
// (16% peak) nor VALU (12%). Fix: merge z-adjacent tap pairs into one
// unaligned float2 load (8 -> 4 gather instructions), + XCD slab swizzle.

constexpr int H = 128, W = 128, D = 128;
constexpr int N = H * W * D;      // 2^21
constexpr int B = 2;

typedef float f2 __attribute__((ext_vector_type(2)));
typedef f2 uf2 __attribute__((aligned(4)));   // 4B-aligned float2 (unaligned dwordx2 ok on gfx950)

__global__ __launch_bounds__(256) void warp_kernel(
    const float* __restrict__ image,
    const float* __restrict__ ddf,
    float* __restrict__ out)
{
    // XCD-aware swizzle: give each XCD a contiguous slab of the volume so its
    // L2 caches a disjoint region (round-robin dispatch otherwise makes all 8
    // XCDs fetch the same lines). Grid is 16384 = 8 * 2048.
    int bid = blockIdx.x;
    int nper = gridDim.x >> 3;
    int newbid = (bid & 7) * nper + (bid >> 3);
    int tid = newbid * 256 + threadIdx.x;

    int b   = tid >> 21;          // N = 2^21
    int lin = tid & (N - 1);
    int h = lin >> 14;            // W*D = 2^14
    int w = (lin >> 7) & 127;
    int d = lin & 127;

    const float* ddfb = ddf + (size_t)b * 3 * N + lin;
    float x = (float)h + ddfb[0];
    float y = (float)w + ddfb[N];
    float z = (float)d + ddfb[2 * N];

    float xf = floorf(x), yf = floorf(y), zf = floorf(z);
    float fx = x - xf, fy = y - yf, fz = z - zf;
    int x0 = (int)xf, y0 = (int)yf, z0 = (int)zf;
    int x1 = x0 + 1, y1 = y0 + 1, z1 = z0 + 1;

    // Per-axis weights with zero-padding folded in (weight=0 if OOB).
    bool vx0 = (unsigned)x0 < (unsigned)H;
    bool vx1 = (unsigned)x1 < (unsigned)H;
    bool vy0 = (unsigned)y0 < (unsigned)W;
    bool vy1 = (unsigned)y1 < (unsigned)W;
    bool vz0 = (unsigned)z0 < (unsigned)D;
    bool vz1 = (unsigned)z1 < (unsigned)D;

    float ax0 = vx0 ? (1.0f - fx) : 0.0f;
    float ax1 = vx1 ? fx          : 0.0f;
    float ay0 = vy0 ? (1.0f - fy) : 0.0f;
    float ay1 = vy1 ? fy          : 0.0f;
    float az0 = vz0 ? (1.0f - fz) : 0.0f;
    float az1 = vz1 ? fz          : 0.0f;

    // Clamped x/y indices (weight already zeroed when OOB).
    int cx0 = vx0 ? x0 : 0;
    int cx1 = vx1 ? x1 : 0;
    int cy0 = vy0 ? y0 : 0;
    int cy1 = vy1 ? y1 : 0;

    // z-pair base clamped to [0, D-2]; 'zlo' tells which component is v(z0).
    int zb = z0 < 0 ? 0 : (z0 > D - 2 ? D - 2 : z0);
    bool zlo = (z0 == zb);

    const float* img = image + (size_t)b * N;
    int rx0 = cx0 << 14, rx1 = cx1 << 14;   // x * W*D
    int ry0 = cy0 << 7,  ry1 = cy1 << 7;    // y * D

    f2 p00 = *(const uf2*)(img + rx0 + ry0 + zb);
    f2 p01 = *(const uf2*)(img + rx0 + ry1 + zb);
    f2 p10 = *(const uf2*)(img + rx1 + ry0 + zb);
    f2 p11 = *(const uf2*)(img + rx1 + ry1 + zb);

    // Component select: z0==zb -> (x,y) = (v_z0, v_z1); z0 clamped down
    // (z0==127) -> v_z0 = .y (v_z1 weight 0); z0==-1 -> v_z1 = .x (v_z0 w=0).
    float v000 = zlo ? p00.x : p00.y;
    float v001 = zlo ? p00.y : p00.x;
    float v010 = zlo ? p01.x : p01.y;
    float v011 = zlo ? p01.y : p01.x;
    float v100 = zlo ? p10.x : p10.y;
    float v101 = zlo ? p10.y : p10.x;
    float v110 = zlo ? p11.x : p11.y;
    float v111 = zlo ? p11.y : p11.x;

    float acc =
        ax0 * (ay0 * (az0 * v000 + az1 * v001) +
               ay1 * (az0 * v010 + az1 * v011)) +
        ax1 * (ay0 * (az0 * v100 + az1 * v101) +
               ay1 * (az0 * v110 + az1 * v111));

    out[tid] = acc;
}

extern "C" void kernel_launch(void* const* d_in, const int* in_sizes, int n_in,
                              void* d_out, int out_size, void* d_ws, size_t ws_size,
                              hipStream_t stream) {
    const float* image = (const float*)d_in[0];
    const float* ddf   = (const float*)d_in[1];
    float* out = (float*)d_out;

    int total = B * N;                      // 4,194,304
    int block = 256;
    int grid = (total + block - 1) / block; // 16384
    warp_kernel<<<grid, block, 0, stream>>>(image, ddf, out);
}

// Round 3
// 138.459 us; speedup vs baseline: 1.1555x; 1.0705x over previous
//
#include <hip/hip_runtime.h>
#include <hip/hip_fp16.h>

// Warp: trilinear grid_sample, padding_mode='zeros', align_corners=true.
// image: (B=2, C=1, H=128, W=128, D=128) fp32
// ddf:   (B=2, 3, H, W, D) fp32, voxel-unit displacements
// out:   (B, C, H, W, D) fp32
//
// R2 analysis: bound by scattered cache-line request rate (~0.4 line-req/cy/CU;
// HBM 9.5%, VALU 14%). Row-major layout costs ~4.1 distinct 128B lines per
// trilinear stencil (4 rows). Fix: pre-pass relayout image -> fp16 bricks,
// one 128B line = 4x4x4 voxel cube => E[lines/stencil] = 1.25^3 ~= 1.95.
// Accuracy budget: threshold 7.56e-2, fp16 image adds ~3e-3 on top of 7.8e-3.

constexpr int H = 128, W = 128, D = 128;
constexpr int N = H * W * D;      // 2^21
constexpr int B = 2;

typedef float f2 __attribute__((ext_vector_type(2)));
typedef f2 uf2 __attribute__((aligned(4)));
typedef unsigned short us4 __attribute__((ext_vector_type(4)));

// Bricked fp16 address: brick grid 32^3, brick = 4x4x4 voxels = 64 fp16 = 128B.
// bits: x>>2 -> [16:20], y>>2 -> [11:15], z>>2 -> [6:10],
//       x&3 -> [4:5],   y&3 -> [2:3],   z&3 -> [0:1]   (disjoint -> OR)
__device__ __forceinline__ int paddr(int x, int y, int z) {
    return ((x >> 2) << 16) | ((y >> 2) << 11) | ((z >> 2) << 6)
         | ((x & 3) << 4) | ((y & 3) << 2) | (z & 3);
}

// Pre-pass: fp32 row-major -> fp16 bricked. One thread = one z-column of a
// brick (4 consecutive bricked elements = z&3 of 0..3 with x,y fixed).
__global__ __launch_bounds__(256) void brick_kernel(
    const float* __restrict__ image,
    __half* __restrict__ bricks)
{
    int t = blockIdx.x * blockDim.x + threadIdx.x;   // B*N/4 threads
    int o = t << 2;                                  // bricked element index
    int b = o >> 21;
    int q = o & (N - 1);
    int brick = q >> 6;
    int within = q & 63;
    int x = (((brick >> 10) & 31) << 2) | ((within >> 4) & 3);
    int y = (((brick >> 5) & 31) << 2) | ((within >> 2) & 3);
    int z = (brick & 31) << 2;                       // within&3 == 0

    const float4 v = *(const float4*)(image + ((size_t)b << 21) + (x << 14) + (y << 7) + z);
    us4 p;
    p.x = __half_as_ushort(__float2half_rn(v.x));
    p.y = __half_as_ushort(__float2half_rn(v.y));
    p.z = __half_as_ushort(__float2half_rn(v.z));
    p.w = __half_as_ushort(__float2half_rn(v.w));
    *(us4*)((unsigned short*)bricks + o) = p;
}

__global__ __launch_bounds__(256) void warp_brick_kernel(
    const __half* __restrict__ bricks,
    const float* __restrict__ ddf,
    float* __restrict__ out)
{
    // XCD slab swizzle (grid 16384 = 8 * 2048): disjoint L2 working sets.
    int bid = blockIdx.x;
    int nper = gridDim.x >> 3;
    int newbid = (bid & 7) * nper + (bid >> 3);
    int tid = newbid * 256 + threadIdx.x;

    int b   = tid >> 21;
    int lin = tid & (N - 1);
    int h = lin >> 14;
    int w = (lin >> 7) & 127;
    int d = lin & 127;

    const float* ddfb = ddf + (size_t)b * 3 * N + lin;
    float x = (float)h + ddfb[0];
    float y = (float)w + ddfb[N];
    float z = (float)d + ddfb[2 * N];

    float xf = floorf(x), yf = floorf(y), zf = floorf(z);
    float fx = x - xf, fy = y - yf, fz = z - zf;
    int x0 = (int)xf, y0 = (int)yf, z0 = (int)zf;
    int x1 = x0 + 1, y1 = y0 + 1, z1 = z0 + 1;

    bool vx0 = (unsigned)x0 < (unsigned)H;
    bool vx1 = (unsigned)x1 < (unsigned)H;
    bool vy0 = (unsigned)y0 < (unsigned)W;
    bool vy1 = (unsigned)y1 < (unsigned)W;
    bool vz0 = (unsigned)z0 < (unsigned)D;
    bool vz1 = (unsigned)z1 < (unsigned)D;

    float ax0 = vx0 ? (1.0f - fx) : 0.0f;
    float ax1 = vx1 ? fx          : 0.0f;
    float ay0 = vy0 ? (1.0f - fy) : 0.0f;
    float ay1 = vy1 ? fy          : 0.0f;
    float az0 = vz0 ? (1.0f - fz) : 0.0f;
    float az1 = vz1 ? fz          : 0.0f;

    int cx0 = vx0 ? x0 : 0;
    int cx1 = vx1 ? x1 : 0;
    int cy0 = vy0 ? y0 : 0;
    int cy1 = vy1 ? y1 : 0;
    int cz0 = vz0 ? z0 : 0;
    int cz1 = vz1 ? z1 : 0;

    // Per-axis bricked address components (bit-disjoint).
    int X0 = ((cx0 >> 2) << 16) | ((cx0 & 3) << 4);
    int X1 = ((cx1 >> 2) << 16) | ((cx1 & 3) << 4);
    int Y0 = ((cy0 >> 2) << 11) | ((cy0 & 3) << 2);
    int Y1 = ((cy1 >> 2) << 11) | ((cy1 & 3) << 2);
    int Z0 = ((cz0 >> 2) << 6) | (cz0 & 3);
    int Z1 = ((cz1 >> 2) << 6) | (cz1 & 3);

    const __half* img = bricks + ((size_t)b << 21);
    float v000 = __half2float(img[X0 | Y0 | Z0]);
    float v001 = __half2float(img[X0 | Y0 | Z1]);
    float v010 = __half2float(img[X0 | Y1 | Z0]);
    float v011 = __half2float(img[X0 | Y1 | Z1]);
    float v100 = __half2float(img[X1 | Y0 | Z0]);
    float v101 = __half2float(img[X1 | Y0 | Z1]);
    float v110 = __half2float(img[X1 | Y1 | Z0]);
    float v111 = __half2float(img[X1 | Y1 | Z1]);

    float acc =
        ax0 * (ay0 * (az0 * v000 + az1 * v001) +
               ay1 * (az0 * v010 + az1 * v011)) +
        ax1 * (ay0 * (az0 * v100 + az1 * v101) +
               ay1 * (az0 * v110 + az1 * v111));

    out[tid] = acc;
}

// ---- Fallback (R2 path) if ws is too small for the fp16 bricks ----
__global__ __launch_bounds__(256) void warp_kernel(
    const float* __restrict__ image,
    const float* __restrict__ ddf,
    float* __restrict__ out)
{
    int bid = blockIdx.x;
    int nper = gridDim.x >> 3;
    int newbid = (bid & 7) * nper + (bid >> 3);
    int tid = newbid * 256 + threadIdx.x;

    int b   = tid >> 21;
    int lin = tid & (N - 1);
    int h = lin >> 14;
    int w = (lin >> 7) & 127;
    int d = lin & 127;

    const float* ddfb = ddf + (size_t)b * 3 * N + lin;
    float x = (float)h + ddfb[0];
    float y = (float)w + ddfb[N];
    float z = (float)d + ddfb[2 * N];

    float xf = floorf(x), yf = floorf(y), zf = floorf(z);
    float fx = x - xf, fy = y - yf, fz = z - zf;
    int x0 = (int)xf, y0 = (int)yf, z0 = (int)zf;
    int x1 = x0 + 1, y1 = y0 + 1, z1 = z0 + 1;

    bool vx0 = (unsigned)x0 < (unsigned)H;
    bool vx1 = (unsigned)x1 < (unsigned)H;
    bool vy0 = (unsigned)y0 < (unsigned)W;
    bool vy1 = (unsigned)y1 < (unsigned)W;
    bool vz0 = (unsigned)z0 < (unsigned)D;
    bool vz1 = (unsigned)z1 < (unsigned)D;

    float ax0 = vx0 ? (1.0f - fx) : 0.0f;
    float ax1 = vx1 ? fx          : 0.0f;
    float ay0 = vy0 ? (1.0f - fy) : 0.0f;
    float ay1 = vy1 ? fy          : 0.0f;
    float az0 = vz0 ? (1.0f - fz) : 0.0f;
    float az1 = vz1 ? fz          : 0.0f;

    int cx0 = vx0 ? x0 : 0;
    int cx1 = vx1 ? x1 : 0;
    int cy0 = vy0 ? y0 : 0;
    int cy1 = vy1 ? y1 : 0;

    int zb = z0 < 0 ? 0 : (z0 > D - 2 ? D - 2 : z0);
    bool zlo = (z0 == zb);

    const float* img = image + (size_t)b * N;
    int rx0 = cx0 << 14, rx1 = cx1 << 14;
    int ry0 = cy0 << 7,  ry1 = cy1 << 7;

    f2 p00 = *(const uf2*)(img + rx0 + ry0 + zb);
    f2 p01 = *(const uf2*)(img + rx0 + ry1 + zb);
    f2 p10 = *(const uf2*)(img + rx1 + ry0 + zb);
    f2 p11 = *(const uf2*)(img + rx1 + ry1 + zb);

    float v000 = zlo ? p00.x : p00.y;
    float v001 = zlo ? p00.y : p00.x;
    float v010 = zlo ? p01.x : p01.y;
    float v011 = zlo ? p01.y : p01.x;
    float v100 = zlo ? p10.x : p10.y;
    float v101 = zlo ? p10.y : p10.x;
    float v110 = zlo ? p11.x : p11.y;
    float v111 = zlo ? p11.y : p11.x;

    float acc =
        ax0 * (ay0 * (az0 * v000 + az1 * v001) +
               ay1 * (az0 * v010 + az1 * v011)) +
        ax1 * (ay0 * (az0 * v100 + az1 * v101) +
               ay1 * (az0 * v110 + az1 * v111));

    out[tid] = acc;
}

extern "C" void kernel_launch(void* const* d_in, const int* in_sizes, int n_in,
                              void* d_out, int out_size, void* d_ws, size_t ws_size,
                              hipStream_t stream) {
    const float* image = (const float*)d_in[0];
    const float* ddf   = (const float*)d_in[1];
    float* out = (float*)d_out;

    int total = B * N;                      // 4,194,304
    int block = 256;
    int grid = total / block;               // 16384

    size_t brick_bytes = (size_t)B * N * sizeof(__half);   // 8 MiB
    if (ws_size >= brick_bytes) {
        __half* bricks = (__half*)d_ws;
        brick_kernel<<<total / 4 / block, block, 0, stream>>>(image, bricks);
        warp_brick_kernel<<<grid, block, 0, stream>>>(bricks, ddf, out);
    } else {
        warp_kernel<<<grid, block, 0, stream>>>(image, ddf, out);
    }
}